// Round 8
// baseline (399.956 us; speedup 1.0000x reference)
//
#include <hip/hip_runtime.h>

#define N_TOK 65536
#define DIN   256
#define DOUT  256
#define NEXP  8

typedef __bf16 bf16x8 __attribute__((ext_vector_type(8)));
typedef float  f32x4  __attribute__((ext_vector_type(4)));

// ---------------------------------------------------------------------------
// prep: Wt[e][n][k] = bf16(We[e][k][n]) via LDS-tiled transpose (coalesced
// both directions). grid = 8 experts * 16 tiles of 64x64, block = 256.
// ---------------------------------------------------------------------------
__global__ __launch_bounds__(256) void prep_kernel(const float* __restrict__ We,
                                                   __bf16* __restrict__ Wt) {
  __shared__ float T[64 * 65];
  int bid = blockIdx.x;
  int e = bid >> 4;
  int tk = (bid >> 2) & 3, tn = bid & 3;
  int k0 = tk * 64, n0 = tn * 64;
  int tid = threadIdx.x;
  int cr = tid >> 6;     // 0..3
  int cc = tid & 63;     // coalesced lane dim
#pragma unroll
  for (int i = 0; i < 16; i++) {
    int k = i * 4 + cr;
    T[cc * 65 + k] = We[(size_t)(e * 256 + k0 + k) * 256 + n0 + cc];  // read n-contig
  }
  __syncthreads();
#pragma unroll
  for (int i = 0; i < 16; i++) {
    int n = i * 4 + cr;
    Wt[(size_t)(e * 256 + n0 + n) * 256 + k0 + cc] = (__bf16)T[n * 65 + cc];  // write k-contig
  }
}

// ---------------------------------------------------------------------------
// fused MoE: router + dense-combine expert GEMM in ONE kernel.
// Block = 256 threads (4 waves) = 64 tokens x all 256 output cols. Grid 1024.
//
// Dense-combine math: out = sum_e combine[n,e]*(x@We + be) where combine has
// exactly two nonzeros (wa, 1-wa). Adding the 6 zero-weight terms (0*y == 0
// exactly in fp32) is bit-equivalent to the 2-term sum, so computing ALL 8
// experts densely (4x MFMA, ~8.5us chip-wide) removes every indirection:
// no buckets/atomics, no token gather, no scattered writes, no xb workspace.
//
// Phases (6 barriers total):
//  1 stage: x f32 -> bf16 LDS tile Xb[64][256], XOR-octet swizzle
//    (slot j' of row r holds global octet j'^(r&7); dense 1KB global reads).
//  2 logits: fp32 from global x (L2-hot after stage), split-K across the 4
//    waves (Wr wave-uniform -> s_load), partials to LDS P in fixed order.
//  3 select (threads 0..63): reduce, top-2, 5e-3 guard with canonical fp64
//    fallback (np-selection-safe, unchanged), weight wb = sigmoid(diff);
//    write dense combine C8[e][tok] (zeroed in phase 0).
//  4 per-expert GEMM: A from LDS (staged once, read 8x), B = Wt from global
//    (1MB, L2-resident). After each expert's full K: oacc += w_e*(y_e + be)
//    -- f32x4 VALU, w_e per 4-row group via one ds_read_b128 from C8.
//  5 epilogue: acc -> LDS (reuse Xb, 2 col-halves, 2-way-free XOR swizzle)
//    -> 512B-contiguous float4 row stores (full cache lines, dense rows).
// ---------------------------------------------------------------------------
__global__ __launch_bounds__(256, 2) void moe_fused_kernel(const float* __restrict__ x,
                                                           const float* __restrict__ Wr,
                                                           const __bf16* __restrict__ Wt,
                                                           const float* __restrict__ be,
                                                           float* __restrict__ out) {
  __shared__ __bf16 Xb[64 * 256];   // 32KB bf16 A-tile (swizzled octets); reused as epilogue f32 buf
  __shared__ float P[64 * 36];      // 9KB logit partials [token][wave*8+e]
  __shared__ float C8[NEXP * 64];   // 2KB dense combine [e][token]

  const int tid = threadIdx.x;
  const int tokBase = blockIdx.x * 64;

  // phase 0: zero the dense combine table
  C8[tid] = 0.f;
  C8[tid + 256] = 0.f;

  // ---- phase 1: stage x -> bf16 LDS (reg roundtrip, XOR-octet swizzle) ----
  {
    const int srow = tid >> 5;          // 0..7
    const int so   = tid & 31;          // slot octet (16B unit)
    const int s8   = so ^ (srow & 7);   // global octet fetched ((row&7) const over i)
#pragma unroll
    for (int i = 0; i < 8; i++) {
      int row = srow + 8 * i;
      const float* src = &x[(size_t)(tokBase + row) * DIN + s8 * 8];
      float4 u0 = *(const float4*)src;
      float4 u1 = *(const float4*)(src + 4);
      bf16x8 pk;
      pk[0] = (__bf16)u0.x; pk[1] = (__bf16)u0.y; pk[2] = (__bf16)u0.z; pk[3] = (__bf16)u0.w;
      pk[4] = (__bf16)u1.x; pk[5] = (__bf16)u1.y; pk[6] = (__bf16)u1.z; pk[7] = (__bf16)u1.w;
      *(bf16x8*)&Xb[(row * 32 + so) * 8] = pk;
    }
  }

  // ---- phase 2: router logits fp32, split-K across 4 waves ----
  const int w = __builtin_amdgcn_readfirstlane(tid >> 6);  // wave id 0..3
  const int t = tid & 63;                                  // lane = token-in-block
  const int token = tokBase + t;
  {
    float a8[NEXP];
#pragma unroll
    for (int e = 0; e < NEXP; e++) a8[e] = 0.f;
#pragma unroll
    for (int i4 = 0; i4 < 16; i4++) {
      int k = w * 64 + i4 * 4;
      float4 xv = *(const float4*)&x[(size_t)token * DIN + k];   // L2-hot (phase 1)
      const float* w0 = &Wr[k * NEXP];                           // wave-uniform -> s_load
#pragma unroll
      for (int e = 0; e < NEXP; e++)
        a8[e] += xv.x * w0[e] + xv.y * w0[NEXP + e] + xv.z * w0[2 * NEXP + e] + xv.w * w0[3 * NEXP + e];
    }
    f32x4 lo, hi;
#pragma unroll
    for (int e = 0; e < 4; e++) { lo[e] = a8[e]; hi[e] = a8[4 + e]; }
    *(f32x4*)&P[t * 36 + w * 8]     = lo;
    *(f32x4*)&P[t * 36 + w * 8 + 4] = hi;
  }
  __syncthreads();

  // ---- phase 3: per-token select + weights (threads 0..63) ----
  if (tid < 64) {
    f32x4 pa0 = *(const f32x4*)&P[tid * 36 + 0];
    f32x4 pa1 = *(const f32x4*)&P[tid * 36 + 8];
    f32x4 pa2 = *(const f32x4*)&P[tid * 36 + 16];
    f32x4 pa3 = *(const f32x4*)&P[tid * 36 + 24];
    f32x4 pb0 = *(const f32x4*)&P[tid * 36 + 4];
    f32x4 pb1 = *(const f32x4*)&P[tid * 36 + 12];
    f32x4 pb2 = *(const f32x4*)&P[tid * 36 + 20];
    f32x4 pb3 = *(const f32x4*)&P[tid * 36 + 28];
    f32x4 sA = ((pa0 + pa1) + pa2) + pa3;
    f32x4 sB = ((pb0 + pb1) + pb2) + pb3;
    float lg[NEXP];
#pragma unroll
    for (int e = 0; e < 4; e++) { lg[e] = sA[e]; lg[4 + e] = sB[e]; }

    int best = 0;
#pragma unroll
    for (int e = 1; e < NEXP; e++) if (lg[e] > lg[best]) best = e;
    int sec = (best == 0) ? 1 : 0;
#pragma unroll
    for (int e = 0; e < NEXP; e++)
      if (e != best && e != sec && lg[e] > lg[sec]) sec = e;
    float l3 = -1e30f;
#pragma unroll
    for (int e = 0; e < NEXP; e++)
      if (e != best && e != sec) l3 = fmaxf(l3, lg[e]);

    float diff = lg[sec] - lg[best];        // <= 0
    bool need = (lg[sec] - l3) < 5e-3f;     // 2nd-vs-3rd near-tie -> fp64
    if (__any(need)) {
      if (need) {
        const float4* xr = (const float4*)(x + (size_t)token * DIN);
        double d[NEXP];
#pragma unroll
        for (int e = 0; e < NEXP; e++) d[e] = 0.0;
        for (int i4 = 0; i4 < DIN / 4; i4++) {
          float4 vv = xr[i4];
          const float* w0 = &Wr[(i4 * 4) * NEXP];
#pragma unroll
          for (int e = 0; e < NEXP; e++)
            d[e] += (double)vv.x * w0[e] + (double)vv.y * w0[NEXP + e] +
                    (double)vv.z * w0[2 * NEXP + e] + (double)vv.w * w0[3 * NEXP + e];
        }
        best = 0;
#pragma unroll
        for (int e = 1; e < NEXP; e++) if (d[e] > d[best]) best = e;
        sec = (best == 0) ? 1 : 0;
#pragma unroll
        for (int e = 0; e < NEXP; e++)
          if (e != best && e != sec && d[e] > d[sec]) sec = e;
        diff = (float)(d[sec] - d[best]);
      }
    }

    float wb = 1.f / (1.f + expf(diff));    // weight of `best` after renorm
    int a, b2; float wa;
    if (best < sec) { a = best; b2 = sec; wa = wb; }
    else            { a = sec;  b2 = best; wa = 1.f - wb; }
    C8[a * 64 + tid]  = wa;
    C8[b2 * 64 + tid] = 1.f - wa;
  }
  __syncthreads();

  // ---- phase 4: dense-combine expert GEMM ----
  const int lane = tid & 63;
  const int c16 = lane & 15, quad = lane >> 4;
  const int wid = tid >> 6;                 // wave = 64-col quarter

  f32x4 oacc[4][4];
#pragma unroll
  for (int mi = 0; mi < 4; mi++)
#pragma unroll
    for (int ni = 0; ni < 4; ni++)
#pragma unroll
      for (int r = 0; r < 4; r++) oacc[mi][ni][r] = 0.f;

  for (int e = 0; e < NEXP; e++) {
    f32x4 t4[4][4];
#pragma unroll
    for (int mi = 0; mi < 4; mi++)
#pragma unroll
      for (int ni = 0; ni < 4; ni++)
#pragma unroll
        for (int r = 0; r < 4; r++) t4[mi][ni][r] = 0.f;

#pragma unroll
    for (int kk = 0; kk < 8; kk++) {
      bf16x8 af[4];
#pragma unroll
      for (int mi = 0; mi < 4; mi++) {
        int row = mi * 16 + c16;
        int phys = (kk * 4 + quad) ^ (row & 7);
        af[mi] = *(const bf16x8*)&Xb[(row * 32 + phys) * 8];
      }
#pragma unroll
      for (int ni = 0; ni < 4; ni++) {
        int col = wid * 64 + ni * 16 + c16;
        bf16x8 bv = *(const bf16x8*)&Wt[((size_t)e * DOUT + col) * DIN + kk * 32 + quad * 8];
#pragma unroll
        for (int mi = 0; mi < 4; mi++)
          t4[mi][ni] = __builtin_amdgcn_mfma_f32_16x16x32_bf16(af[mi], bv, t4[mi][ni], 0, 0, 0);
      }
    }
    // weighted accumulate: oacc += w_e[row] * (y_e + be[e][col])
#pragma unroll
    for (int mi = 0; mi < 4; mi++) {
      f32x4 wv = *(const f32x4*)&C8[e * 64 + mi * 16 + quad * 4];
#pragma unroll
      for (int ni = 0; ni < 4; ni++) {
        float bias = be[e * DOUT + wid * 64 + ni * 16 + c16];
        oacc[mi][ni] += wv * (t4[mi][ni] + bias);
      }
    }
  }

  // ---- phase 5: coalesced epilogue via LDS (two 128-col halves) ----
  float* OF = (float*)Xb;     // 32KB = [64][128] f32, col-XOR swizzled
#pragma unroll
  for (int h = 0; h < 2; h++) {
    __syncthreads();          // Xb/OF free (previous readers done)
    if ((wid >> 1) == h) {    // waves covering cols h*128 .. h*128+127
#pragma unroll
      for (int mi = 0; mi < 4; mi++)
#pragma unroll
        for (int ni = 0; ni < 4; ni++)
#pragma unroll
          for (int r = 0; r < 4; r++) {
            int row = mi * 16 + quad * 4 + r;
            int colh = (wid & 1) * 64 + ni * 16 + c16;
            OF[row * 128 + (colh ^ ((row & 7) << 2))] = oacc[mi][ni][r];
          }
    }
    __syncthreads();
#pragma unroll
    for (int i = 0; i < 8; i++) {
      int seg = tid + 256 * i;
      int row = seg >> 5, cs = seg & 31;
      f32x4 v = *(const f32x4*)&OF[row * 128 + ((cs * 4) ^ ((row & 7) << 2))];
      *(f32x4*)&out[(size_t)(tokBase + row) * DOUT + h * 128 + cs * 4] = v;
    }
  }
}

// ---------------------------------------------------------------------------
extern "C" void kernel_launch(void* const* d_in, const int* in_sizes, int n_in,
                              void* d_out, int out_size, void* d_ws, size_t ws_size,
                              hipStream_t stream) {
  const float* x  = (const float*)d_in[0];
  const float* Wr = (const float*)d_in[1];
  const float* We = (const float*)d_in[2];
  const float* be = (const float*)d_in[3];
  float* out = (float*)d_out;

  // ws layout: [0, 1MB) : Wt bf16 [8][256][256] ([e][n][k]). Nothing else.
  __bf16* Wt = (__bf16*)d_ws;

  prep_kernel<<<128, 256, 0, stream>>>(We, Wt);
  moe_fused_kernel<<<N_TOK / 64, 256, 0, stream>>>(x, Wr, Wt, be, out);
}